// Round 3
// baseline (1080558.008 us; speedup 1.0000x reference)
//
#include <hip/hip_runtime.h>

#define T_STEPS 32768
#define HID 1024
#define RPG 16           // rows per workgroup
#define NROLES 64        // workgroups per XCD replica group (64*16 = 1024 rows)
#define NXCD 8
#define NWG_LAUNCH 768   // >= 64 on every XCD under round-robin dispatch
#define PROBE_CAP 32768  // step-1 visibility probe spins (few ms worst case)
#define RUN_CAP (1 << 20) // steady-state poll cap (~100+ ms; never legit-triggers)
#define REG_TICKS 1000000ll  // ~10 ms @ 100 MHz s_memrealtime

typedef unsigned long long ull;
typedef ull ullx2 __attribute__((ext_vector_type(2)));

// ---------------- bf16 helpers (manual, RNE) ----------------
__device__ __forceinline__ unsigned short f2bf(float f) {
    unsigned u = __float_as_uint(f);
    u = (u + 0x7fffu + ((u >> 16) & 1u)) >> 16;
    return (unsigned short)u;
}
__device__ __forceinline__ float bf2f(unsigned short s) {
    return __uint_as_float(((unsigned)s) << 16);
}

// ---------------- Kernel 1: pre[t][j] = x[t,:] . W_x[j,:] + b_i2h[j] ----------------
// Also resets the rnn_rec control block and scrubs hp_all tags (0xFFFFFFFF
// never matches a poll target). Stream ordering + kernel-boundary flush makes
// this visible to rnn_rec regardless of mode. No hipMemsetAsync needed.
#define BM 64
#define BN 64
#define BK 16
#define LDST 68

__global__ void __launch_bounds__(256) pre_gemm(
    const float* __restrict__ x, const float* __restrict__ Wi,
    const float* __restrict__ b, unsigned short* __restrict__ pre,
    ull* __restrict__ hp_all, unsigned* __restrict__ ctl)
{
    __shared__ float As[BK * LDST];
    __shared__ float Bs[BK * LDST];
    const int tid = threadIdx.x;

    if (blockIdx.y == 0 && blockIdx.x == 0 && tid < 32) ctl[tid] = 0u;
    if (blockIdx.y == 1 && blockIdx.x < 64)
        hp_all[(size_t)blockIdx.x * 256 + tid] = 0xFFFFFFFF00000000ull;

    const int t0 = blockIdx.x * BM;
    const int j0 = blockIdx.y * BN;
    const int row = tid >> 2;
    const int kq  = tid & 3;
    const int tx  = tid & 15;
    const int ty  = tid >> 4;

    float c[4][4];
#pragma unroll
    for (int i = 0; i < 4; ++i)
#pragma unroll
        for (int j = 0; j < 4; ++j) c[i][j] = 0.f;

    for (int k0 = 0; k0 < 1024; k0 += BK) {
        float4 a4 = *(const float4*)&x[(size_t)(t0 + row) * 1024 + k0 + 4 * kq];
        float4 b4 = *(const float4*)&Wi[(size_t)(j0 + row) * 2048 + k0 + 4 * kq];
        __syncthreads();
        As[(4 * kq + 0) * LDST + row] = a4.x;
        As[(4 * kq + 1) * LDST + row] = a4.y;
        As[(4 * kq + 2) * LDST + row] = a4.z;
        As[(4 * kq + 3) * LDST + row] = a4.w;
        Bs[(4 * kq + 0) * LDST + row] = b4.x;
        Bs[(4 * kq + 1) * LDST + row] = b4.y;
        Bs[(4 * kq + 2) * LDST + row] = b4.z;
        Bs[(4 * kq + 3) * LDST + row] = b4.w;
        __syncthreads();
#pragma unroll
        for (int kk = 0; kk < BK; ++kk) {
            float4 av = *(const float4*)&As[kk * LDST + 4 * ty];
            float4 bv = *(const float4*)&Bs[kk * LDST + 4 * tx];
            c[0][0] = fmaf(av.x, bv.x, c[0][0]); c[0][1] = fmaf(av.x, bv.y, c[0][1]);
            c[0][2] = fmaf(av.x, bv.z, c[0][2]); c[0][3] = fmaf(av.x, bv.w, c[0][3]);
            c[1][0] = fmaf(av.y, bv.x, c[1][0]); c[1][1] = fmaf(av.y, bv.y, c[1][1]);
            c[1][2] = fmaf(av.y, bv.z, c[1][2]); c[1][3] = fmaf(av.y, bv.w, c[1][3]);
            c[2][0] = fmaf(av.z, bv.x, c[2][0]); c[2][1] = fmaf(av.z, bv.y, c[2][1]);
            c[2][2] = fmaf(av.z, bv.z, c[2][2]); c[2][3] = fmaf(av.z, bv.w, c[2][3]);
            c[3][0] = fmaf(av.w, bv.x, c[3][0]); c[3][1] = fmaf(av.w, bv.y, c[3][1]);
            c[3][2] = fmaf(av.w, bv.z, c[3][2]); c[3][3] = fmaf(av.w, bv.w, c[3][3]);
        }
    }

    float4 bias = *(const float4*)&b[j0 + 4 * tx];
#pragma unroll
    for (int i = 0; i < 4; ++i) {
        int r = t0 + 4 * ty + i;
        ushort4 u;
        u.x = f2bf(c[i][0] + bias.x);
        u.y = f2bf(c[i][1] + bias.y);
        u.z = f2bf(c[i][2] + bias.z);
        u.w = f2bf(c[i][3] + bias.w);
        *(ushort4*)&pre[(size_t)r * 1024 + j0 + 4 * tx] = u;
    }
}

// ---------------- Kernel 2: XCD-replicated recurrence, dual-mode ----------------

__device__ __forceinline__ ull pack_hv(float v, unsigned t) {
    return ((ull)t << 32) | (ull)__float_as_uint(v);
}

// h store: FAST = plain write-through (L1 is write-through -> lands in local
// XCD L2). AGENT = baseline relaxed agent atomic (coherence point).
__device__ __forceinline__ void st_h(int fast, ull* p, ull v) {
    if (fast)
        asm volatile("global_store_dwordx2 %0, %1, off" :: "v"(p), "v"(v) : "memory");
    else
        __hip_atomic_store(p, v, __ATOMIC_RELAXED, __HIP_MEMORY_SCOPE_AGENT);
}

// Poll 4 slots until all carry tag tg; returns 1 on cap exhaustion.
// FAST: agent-acquire fence (compiler emits buffer_inv -> L1 invalidate; L1 is
// write-through so inv is always safe) + plain 32B loads -> guaranteed L2 read.
// AGENT: baseline relaxed agent atomic loads.
__device__ __forceinline__ int poll_stage(int fast, const ull* src, float* dst,
                                          unsigned tg, int e0, int cap)
{
    ull p0, p1, p2, p3;
    int spins = 0;
    if (fast) {
        ullx2 a, b;
        for (;;) {
            __builtin_amdgcn_fence(__ATOMIC_ACQUIRE, "agent");
            asm volatile("global_load_dwordx4 %0, %2, off\n\t"
                         "global_load_dwordx4 %1, %2, off offset:16\n\t"
                         "s_waitcnt vmcnt(0)"
                         : "=&v"(a), "=&v"(b) : "v"(&src[e0]) : "memory");
            if ((unsigned)(a.x >> 32) == tg && (unsigned)(a.y >> 32) == tg &&
                (unsigned)(b.x >> 32) == tg && (unsigned)(b.y >> 32) == tg) {
                p0 = a.x; p1 = a.y; p2 = b.x; p3 = b.y;
                break;
            }
            if (++spins > cap) return 1;
        }
    } else {
        for (;;) {
            p0 = __hip_atomic_load(&src[e0 + 0], __ATOMIC_RELAXED, __HIP_MEMORY_SCOPE_AGENT);
            p1 = __hip_atomic_load(&src[e0 + 1], __ATOMIC_RELAXED, __HIP_MEMORY_SCOPE_AGENT);
            p2 = __hip_atomic_load(&src[e0 + 2], __ATOMIC_RELAXED, __HIP_MEMORY_SCOPE_AGENT);
            p3 = __hip_atomic_load(&src[e0 + 3], __ATOMIC_RELAXED, __HIP_MEMORY_SCOPE_AGENT);
            if ((unsigned)(p0 >> 32) == tg && (unsigned)(p1 >> 32) == tg &&
                (unsigned)(p2 >> 32) == tg && (unsigned)(p3 >> 32) == tg) break;
            if (++spins > cap) return 1;
        }
    }
    dst[e0 + 0] = __uint_as_float((unsigned)p0);
    dst[e0 + 1] = __uint_as_float((unsigned)p1);
    dst[e0 + 2] = __uint_as_float((unsigned)p2);
    dst[e0 + 3] = __uint_as_float((unsigned)p3);
    return 0;
}

__device__ __forceinline__ float wave_sum(float v) {
#pragma unroll
    for (int off = 32; off > 0; off >>= 1) v += __shfl_xor(v, off, 64);
    return v;
}

// ctl layout: [0..7] register ctr, [8..15] commit ctr, [16..23] packed vote
// (leader adds 0x10000 | probe_ok; total in hi16, yes-count in lo16 -- single
// location, so no cross-address ordering hazard).
__global__ void __launch_bounds__(256) rnn_rec(
    const unsigned short* __restrict__ pre,
    const float* __restrict__ Wi,
    const float* __restrict__ Wo,
    const float* __restrict__ bo,
    float* __restrict__ out,
    ull* hp_all,
    unsigned* ctl)
{
    unsigned xcd;
    asm volatile("s_getreg_b32 %0, hwreg(HW_REG_XCC_ID)" : "=s"(xcd));
    xcd &= (NXCD - 1);

    const int tid = threadIdx.x;
    __shared__ unsigned s_role, s_go, s_mode;
    __shared__ int s_abort, s_fail;

    if (tid == 0)
        s_role = __hip_atomic_fetch_add(&ctl[xcd], 1u,
                                        __ATOMIC_RELAXED, __HIP_MEMORY_SCOPE_AGENT);
    __syncthreads();
    const unsigned role = s_role;
    if (role >= NROLES) return;   // surplus WG (WG-uniform exit)

    // Two-phase entry: no partial group can ever enter the loop.
    if (tid == 0) {
        unsigned ok = 0;
        long long b0 = (long long)__builtin_amdgcn_s_memrealtime();
        for (;;) {
            if (__hip_atomic_load(&ctl[xcd], __ATOMIC_RELAXED,
                                  __HIP_MEMORY_SCOPE_AGENT) >= NROLES) { ok = 1; break; }
            if ((long long)__builtin_amdgcn_s_memrealtime() - b0 > REG_TICKS) break;
        }
        if (ok) {
            ok = 0;
            __hip_atomic_fetch_add(&ctl[NXCD + xcd], 1u,
                                   __ATOMIC_RELAXED, __HIP_MEMORY_SCOPE_AGENT);
            for (;;) {
                if (__hip_atomic_load(&ctl[NXCD + xcd], __ATOMIC_RELAXED,
                                      __HIP_MEMORY_SCOPE_AGENT) >= NROLES) { ok = 1; break; }
                if ((long long)__builtin_amdgcn_s_memrealtime() - b0 > 2 * REG_TICKS) break;
            }
        }
        s_go = ok;
        s_abort = 0;
        s_fail = 0;
    }
    __syncthreads();
    if (!s_go) return;            // WG-uniform

    ull* hp = hp_all + (size_t)xcd * 2 * HID;

    const int w = tid >> 6;
    const int l = tid & 63;
    const int rowbase = (int)role * RPG + w * 4;
    const int e0 = tid * 4;

    __shared__ float hl[2][HID];

    // W_h fragment resident in VGPRs
    float4 wv[4][4];
#pragma unroll
    for (int rr = 0; rr < 4; ++rr)
#pragma unroll
        for (int j = 0; j < 4; ++j)
            wv[rr][j] = *(const float4*)&Wi[(size_t)(rowbase + rr) * 2048 + 1024 + 4 * l + 256 * j];

    // init h_0 = 0, tag 0, FAST-style (plain write-through)
    if (tid < RPG)
        st_h(1, &hp[(size_t)role * RPG + tid], pack_hv(0.f, 0u));

    // ---- visibility probe (read-only): can we see peers' plain stores via
    // fence+plain loads? Tests both intra-XCD L2 visibility AND correct
    // XCC grouping in one shot. ----
    {
        float scratch[1]; // unused dst trick: reuse hl
        (void)scratch;
        if (poll_stage(1, &hp[0], hl[0], 0u, e0, PROBE_CAP)) s_fail = 1;
        __syncthreads();
    }

    // ---- unanimous vote through one packed agent counter ----
    if (tid == 0) {
        unsigned myok = s_fail ? 0u : 1u;
        __hip_atomic_fetch_add(&ctl[16 + xcd], 0x10000u | myok,
                               __ATOMIC_RELAXED, __HIP_MEMORY_SCOPE_AGENT);
        unsigned v = 0, done = 0;
        long long b0 = (long long)__builtin_amdgcn_s_memrealtime();
        for (;;) {
            v = __hip_atomic_load(&ctl[16 + xcd], __ATOMIC_RELAXED,
                                  __HIP_MEMORY_SCOPE_AGENT);
            if ((v >> 16) >= NROLES) { done = 1; break; }
            if ((long long)__builtin_amdgcn_s_memrealtime() - b0 > 4 * REG_TICKS) break;
        }
        s_go = done;
        s_mode = (done && (v & 0xFFFFu) == NROLES) ? 1u : 0u;
    }
    __syncthreads();
    if (!s_go) return;            // WG-uniform (essentially unreachable)
    const int fast = (int)s_mode;

    // Fallback housekeeping: agent groups on xcd>=2 bow out (avoid 8x MALL
    // contention); xcd 0 and 1 run redundantly. Fast groups all run (L2-local).
    if (!fast && xcd >= 2) return;
    // Agent mode must re-publish init tags at the coherence point (the plain
    // init stores are dirty-in-L2 only).
    if (!fast && tid < RPG)
        st_h(0, &hp[(size_t)role * RPG + tid], pack_hv(0.f, 0u));

    for (int t = 1; t <= T_STEPS; ++t) {
        float prev = 0.f;
        if (l < 4) prev = bf2f(pre[(size_t)(t - 1) * HID + rowbase + l]);

        const ull* src = &hp[((t - 1) & 1) * HID];
        float* dst = hl[(t - 1) & 1];
        if (poll_stage(fast, src, dst, (unsigned)(t - 1), e0, RUN_CAP)) s_abort = 1;
        __syncthreads();
        if (s_abort) break;       // WG-uniform

        float s0 = 0.f, s1 = 0.f, s2 = 0.f, s3 = 0.f;
#pragma unroll
        for (int j = 0; j < 4; ++j) {
            float4 hv = *(const float4*)&dst[4 * l + 256 * j];
            s0 = fmaf(wv[0][j].x, hv.x, s0); s0 = fmaf(wv[0][j].y, hv.y, s0);
            s0 = fmaf(wv[0][j].z, hv.z, s0); s0 = fmaf(wv[0][j].w, hv.w, s0);
            s1 = fmaf(wv[1][j].x, hv.x, s1); s1 = fmaf(wv[1][j].y, hv.y, s1);
            s1 = fmaf(wv[1][j].z, hv.z, s1); s1 = fmaf(wv[1][j].w, hv.w, s1);
            s2 = fmaf(wv[2][j].x, hv.x, s2); s2 = fmaf(wv[2][j].y, hv.y, s2);
            s2 = fmaf(wv[2][j].z, hv.z, s2); s2 = fmaf(wv[2][j].w, hv.w, s2);
            s3 = fmaf(wv[3][j].x, hv.x, s3); s3 = fmaf(wv[3][j].y, hv.y, s3);
            s3 = fmaf(wv[3][j].z, hv.z, s3); s3 = fmaf(wv[3][j].w, hv.w, s3);
        }
        s0 = wave_sum(s0); s1 = wave_sum(s1); s2 = wave_sum(s2); s3 = wave_sum(s3);

        if (l < 4) {
            float sv = (l == 0) ? s0 : (l == 1) ? s1 : (l == 2) ? s2 : s3;
            float h = tanhf(prev + sv);
            st_h(fast, &hp[((size_t)(t & 1)) * HID + rowbase + l],
                 pack_hv(h, (unsigned)t));
        }
        // two-deep parity buffer: no trailing barrier needed (poll success for
        // step t+1 implies all waves finished step t's LDS reads).
    }
    if (s_abort) return;

    // ---- final projection: out = h_T . W_h2o^T + b_h2o ----
    {
        const ull* src = &hp[(T_STEPS & 1) * HID];
        float* dst = hl[0];
        if (poll_stage(fast, src, dst, (unsigned)T_STEPS, e0, RUN_CAP)) s_abort = 1;
        __syncthreads();
        if (s_abort) return;

        float s0 = 0.f, s1 = 0.f, s2 = 0.f, s3 = 0.f;
#pragma unroll
        for (int j = 0; j < 4; ++j) {
            float4 hv = *(const float4*)&dst[4 * l + 256 * j];
            float4 w0 = *(const float4*)&Wo[(size_t)(rowbase + 0) * 1024 + 4 * l + 256 * j];
            float4 w1 = *(const float4*)&Wo[(size_t)(rowbase + 1) * 1024 + 4 * l + 256 * j];
            float4 w2 = *(const float4*)&Wo[(size_t)(rowbase + 2) * 1024 + 4 * l + 256 * j];
            float4 w3 = *(const float4*)&Wo[(size_t)(rowbase + 3) * 1024 + 4 * l + 256 * j];
            s0 = fmaf(w0.x, hv.x, s0); s0 = fmaf(w0.y, hv.y, s0);
            s0 = fmaf(w0.z, hv.z, s0); s0 = fmaf(w0.w, hv.w, s0);
            s1 = fmaf(w1.x, hv.x, s1); s1 = fmaf(w1.y, hv.y, s1);
            s1 = fmaf(w1.z, hv.z, s1); s1 = fmaf(w1.w, hv.w, s1);
            s2 = fmaf(w2.x, hv.x, s2); s2 = fmaf(w2.y, hv.y, s2);
            s2 = fmaf(w2.z, hv.z, s2); s2 = fmaf(w2.w, hv.w, s2);
            s3 = fmaf(w3.x, hv.x, s3); s3 = fmaf(w3.y, hv.y, s3);
            s3 = fmaf(w3.z, hv.z, s3); s3 = fmaf(w3.w, hv.w, s3);
        }
        s0 = wave_sum(s0); s1 = wave_sum(s1); s2 = wave_sum(s2); s3 = wave_sum(s3);
        if (l < 4) {
            float sv = (l == 0) ? s0 : (l == 1) ? s1 : (l == 2) ? s2 : s3;
            out[rowbase + l] = sv + bo[rowbase + l];
        }
    }
}

extern "C" void kernel_launch(void* const* d_in, const int* in_sizes, int n_in,
                              void* d_out, int out_size, void* d_ws, size_t ws_size,
                              hipStream_t stream) {
    const float* x     = (const float*)d_in[0];   // (1, 32768, 1024)
    const float* W_i2h = (const float*)d_in[1];   // (1024, 2048)
    const float* b_i2h = (const float*)d_in[2];   // (1024,)
    const float* W_h2o = (const float*)d_in[3];   // (1024, 1024)
    const float* b_h2o = (const float*)d_in[4];   // (1024,)
    float* out = (float*)d_out;

    unsigned short* pre = (unsigned short*)d_ws;                       // 64 MiB bf16
    ull* hp_all = (ull*)((char*)d_ws + (size_t)T_STEPS * HID * sizeof(unsigned short));
    unsigned* ctl = (unsigned*)((char*)hp_all + (size_t)NXCD * 2 * HID * sizeof(ull));

    pre_gemm<<<dim3(T_STEPS / BM, HID / BN), 256, 0, stream>>>(
        x, W_i2h, b_i2h, pre, hp_all, ctl);
    rnn_rec<<<NWG_LAUNCH, 256, 0, stream>>>(
        pre, W_i2h, W_h2o, b_h2o, out, hp_all, ctl);
}

// Round 4
// 131502.808 us; speedup vs baseline: 8.2170x; 8.2170x over previous
//
#include <hip/hip_runtime.h>

#define T_STEPS 32768
#define HID 1024
#define RPG 16           // rows per workgroup
#define NROLES 64        // workgroups per XCD replica group (64*16 = 1024 rows)
#define NXCD 8
#define NWG_LAUNCH 768   // >= 64 on every XCD under round-robin dispatch
#define PROBE_CAP 32768  // step-1 visibility probe spins (few ms worst case)
#define RUN_CAP (1 << 20) // steady-state poll cap (~100+ ms; never legit-triggers)
#define REG_TICKS 1000000ll  // ~10 ms @ 100 MHz s_memrealtime

typedef unsigned long long ull;
typedef ull ullx2 __attribute__((ext_vector_type(2)));

// ---------------- bf16 helpers (manual, RNE) ----------------
__device__ __forceinline__ unsigned short f2bf(float f) {
    unsigned u = __float_as_uint(f);
    u = (u + 0x7fffu + ((u >> 16) & 1u)) >> 16;
    return (unsigned short)u;
}
__device__ __forceinline__ float bf2f(unsigned short s) {
    return __uint_as_float(((unsigned)s) << 16);
}

// ---------------- Kernel 1: pre[t][j] = x[t,:] . W_x[j,:] + b_i2h[j] ----------------
// Also resets the rnn_rec control block and scrubs hp_all tags (0xFFFFFFFF
// never matches a poll target). Stream ordering + kernel-boundary cache flush
// makes this visible to rnn_rec regardless of mode.
#define BM 64
#define BN 64
#define BK 16
#define LDST 68

__global__ void __launch_bounds__(256) pre_gemm(
    const float* __restrict__ x, const float* __restrict__ Wi,
    const float* __restrict__ b, unsigned short* __restrict__ pre,
    ull* __restrict__ hp_all, unsigned* __restrict__ ctl)
{
    __shared__ float As[BK * LDST];
    __shared__ float Bs[BK * LDST];
    const int tid = threadIdx.x;

    if (blockIdx.y == 0 && blockIdx.x == 0 && tid < 32) ctl[tid] = 0u;
    if (blockIdx.y == 1 && blockIdx.x < 64)
        hp_all[(size_t)blockIdx.x * 256 + tid] = 0xFFFFFFFF00000000ull;

    const int t0 = blockIdx.x * BM;
    const int j0 = blockIdx.y * BN;
    const int row = tid >> 2;
    const int kq  = tid & 3;
    const int tx  = tid & 15;
    const int ty  = tid >> 4;

    float c[4][4];
#pragma unroll
    for (int i = 0; i < 4; ++i)
#pragma unroll
        for (int j = 0; j < 4; ++j) c[i][j] = 0.f;

    for (int k0 = 0; k0 < 1024; k0 += BK) {
        float4 a4 = *(const float4*)&x[(size_t)(t0 + row) * 1024 + k0 + 4 * kq];
        float4 b4 = *(const float4*)&Wi[(size_t)(j0 + row) * 2048 + k0 + 4 * kq];
        __syncthreads();
        As[(4 * kq + 0) * LDST + row] = a4.x;
        As[(4 * kq + 1) * LDST + row] = a4.y;
        As[(4 * kq + 2) * LDST + row] = a4.z;
        As[(4 * kq + 3) * LDST + row] = a4.w;
        Bs[(4 * kq + 0) * LDST + row] = b4.x;
        Bs[(4 * kq + 1) * LDST + row] = b4.y;
        Bs[(4 * kq + 2) * LDST + row] = b4.z;
        Bs[(4 * kq + 3) * LDST + row] = b4.w;
        __syncthreads();
#pragma unroll
        for (int kk = 0; kk < BK; ++kk) {
            float4 av = *(const float4*)&As[kk * LDST + 4 * ty];
            float4 bv = *(const float4*)&Bs[kk * LDST + 4 * tx];
            c[0][0] = fmaf(av.x, bv.x, c[0][0]); c[0][1] = fmaf(av.x, bv.y, c[0][1]);
            c[0][2] = fmaf(av.x, bv.z, c[0][2]); c[0][3] = fmaf(av.x, bv.w, c[0][3]);
            c[1][0] = fmaf(av.y, bv.x, c[1][0]); c[1][1] = fmaf(av.y, bv.y, c[1][1]);
            c[1][2] = fmaf(av.y, bv.z, c[1][2]); c[1][3] = fmaf(av.y, bv.w, c[1][3]);
            c[2][0] = fmaf(av.z, bv.x, c[2][0]); c[2][1] = fmaf(av.z, bv.y, c[2][1]);
            c[2][2] = fmaf(av.z, bv.z, c[2][2]); c[2][3] = fmaf(av.z, bv.w, c[2][3]);
            c[3][0] = fmaf(av.w, bv.x, c[3][0]); c[3][1] = fmaf(av.w, bv.y, c[3][1]);
            c[3][2] = fmaf(av.w, bv.z, c[3][2]); c[3][3] = fmaf(av.w, bv.w, c[3][3]);
        }
    }

    float4 bias = *(const float4*)&b[j0 + 4 * tx];
#pragma unroll
    for (int i = 0; i < 4; ++i) {
        int r = t0 + 4 * ty + i;
        ushort4 u;
        u.x = f2bf(c[i][0] + bias.x);
        u.y = f2bf(c[i][1] + bias.y);
        u.z = f2bf(c[i][2] + bias.z);
        u.w = f2bf(c[i][3] + bias.w);
        *(ushort4*)&pre[(size_t)r * 1024 + j0 + 4 * tx] = u;
    }
}

// ---------------- Kernel 2: XCD-replicated recurrence, dual-mode ----------------
// FAST (proven-visible in R3, now with cheap invalidate): producers use plain
// write-through stores (land in XCD-local L2); consumers poll with
// `buffer_inv sc0` (vector-L1-only invalidate; L1 is write-through so always
// safe) + plain 32B loads -> guaranteed L1 miss, L2 hit. R3's mistake was the
// compiler agent fence (buffer_inv sc1) which invalidates the whole L2 every
// poll iteration -> MALL latency + TCC flood (34.6 us/step). AGENT fallback =
// verbatim baseline atomics (52 ms, proven). Probe + unanimous vote picks the
// mode per XCD group; every failure path is a clean exit, never a hang.

__device__ __forceinline__ ull pack_hv(float v, unsigned t) {
    return ((ull)t << 32) | (ull)__float_as_uint(v);
}

__device__ __forceinline__ void st_h(int fast, ull* p, ull v) {
    if (fast)
        asm volatile("global_store_dwordx2 %0, %1, off" :: "v"(p), "v"(v) : "memory");
    else
        __hip_atomic_store(p, v, __ATOMIC_RELAXED, __HIP_MEMORY_SCOPE_AGENT);
}

// Poll 4 slots until all carry tag tg; returns 1 on cap exhaustion.
__device__ __forceinline__ int poll_stage(int fast, const ull* src, float* dst,
                                          unsigned tg, int e0, int cap)
{
    ull p0, p1, p2, p3;
    int spins = 0;
    if (fast) {
        ullx2 a, b;
        for (;;) {
            // L1-only invalidate, then read from the XCD-shared L2.
            asm volatile("buffer_inv sc0\n\t"
                         "s_waitcnt vmcnt(0)\n\t"
                         "global_load_dwordx4 %0, %2, off\n\t"
                         "global_load_dwordx4 %1, %2, off offset:16\n\t"
                         "s_waitcnt vmcnt(0)"
                         : "=&v"(a), "=&v"(b) : "v"(&src[e0]) : "memory");
            if ((unsigned)(a.x >> 32) == tg && (unsigned)(a.y >> 32) == tg &&
                (unsigned)(b.x >> 32) == tg && (unsigned)(b.y >> 32) == tg) {
                p0 = a.x; p1 = a.y; p2 = b.x; p3 = b.y;
                break;
            }
            if (++spins > cap) return 1;
        }
    } else {
        for (;;) {
            p0 = __hip_atomic_load(&src[e0 + 0], __ATOMIC_RELAXED, __HIP_MEMORY_SCOPE_AGENT);
            p1 = __hip_atomic_load(&src[e0 + 1], __ATOMIC_RELAXED, __HIP_MEMORY_SCOPE_AGENT);
            p2 = __hip_atomic_load(&src[e0 + 2], __ATOMIC_RELAXED, __HIP_MEMORY_SCOPE_AGENT);
            p3 = __hip_atomic_load(&src[e0 + 3], __ATOMIC_RELAXED, __HIP_MEMORY_SCOPE_AGENT);
            if ((unsigned)(p0 >> 32) == tg && (unsigned)(p1 >> 32) == tg &&
                (unsigned)(p2 >> 32) == tg && (unsigned)(p3 >> 32) == tg) break;
            if (++spins > cap) return 1;
        }
    }
    dst[e0 + 0] = __uint_as_float((unsigned)p0);
    dst[e0 + 1] = __uint_as_float((unsigned)p1);
    dst[e0 + 2] = __uint_as_float((unsigned)p2);
    dst[e0 + 3] = __uint_as_float((unsigned)p3);
    return 0;
}

__device__ __forceinline__ float wave_sum(float v) {
#pragma unroll
    for (int off = 32; off > 0; off >>= 1) v += __shfl_xor(v, off, 64);
    return v;
}

// ctl layout: [0..7] register ctr, [8..15] commit ctr, [16..23] packed vote
// (leader adds 0x10000 | probe_ok: total in hi16, yes-count in lo16).
__global__ void __launch_bounds__(256) rnn_rec(
    const unsigned short* __restrict__ pre,
    const float* __restrict__ Wi,
    const float* __restrict__ Wo,
    const float* __restrict__ bo,
    float* __restrict__ out,
    ull* hp_all,
    unsigned* ctl)
{
    unsigned xcd;
    asm volatile("s_getreg_b32 %0, hwreg(HW_REG_XCC_ID)" : "=s"(xcd));
    xcd &= (NXCD - 1);

    const int tid = threadIdx.x;
    __shared__ unsigned s_role, s_go, s_mode;
    __shared__ int s_abort, s_fail;

    if (tid == 0)
        s_role = __hip_atomic_fetch_add(&ctl[xcd], 1u,
                                        __ATOMIC_RELAXED, __HIP_MEMORY_SCOPE_AGENT);
    __syncthreads();
    const unsigned role = s_role;
    if (role >= NROLES) return;   // surplus WG (WG-uniform exit)

    // Two-phase entry: no partial group can ever enter the loop.
    if (tid == 0) {
        unsigned ok = 0;
        long long b0 = (long long)__builtin_amdgcn_s_memrealtime();
        for (;;) {
            if (__hip_atomic_load(&ctl[xcd], __ATOMIC_RELAXED,
                                  __HIP_MEMORY_SCOPE_AGENT) >= NROLES) { ok = 1; break; }
            if ((long long)__builtin_amdgcn_s_memrealtime() - b0 > REG_TICKS) break;
        }
        if (ok) {
            ok = 0;
            __hip_atomic_fetch_add(&ctl[NXCD + xcd], 1u,
                                   __ATOMIC_RELAXED, __HIP_MEMORY_SCOPE_AGENT);
            for (;;) {
                if (__hip_atomic_load(&ctl[NXCD + xcd], __ATOMIC_RELAXED,
                                      __HIP_MEMORY_SCOPE_AGENT) >= NROLES) { ok = 1; break; }
                if ((long long)__builtin_amdgcn_s_memrealtime() - b0 > 2 * REG_TICKS) break;
            }
        }
        s_go = ok;
        s_abort = 0;
        s_fail = 0;
    }
    __syncthreads();
    if (!s_go) return;            // WG-uniform

    ull* hp = hp_all + (size_t)xcd * 2 * HID;

    const int w = tid >> 6;
    const int l = tid & 63;
    const int rowbase = (int)role * RPG + w * 4;
    const int e0 = tid * 4;

    __shared__ float hl[2][HID];

    // W_h fragment resident in VGPRs
    float4 wv[4][4];
#pragma unroll
    for (int rr = 0; rr < 4; ++rr)
#pragma unroll
        for (int j = 0; j < 4; ++j)
            wv[rr][j] = *(const float4*)&Wi[(size_t)(rowbase + rr) * 2048 + 1024 + 4 * l + 256 * j];

    // init h_0 = 0, tag 0, FAST-style (plain write-through)
    if (tid < RPG)
        st_h(1, &hp[(size_t)role * RPG + tid], pack_hv(0.f, 0u));

    // ---- visibility probe (read-only): can we see all peers' plain stores
    // via L1-inv + plain loads? Validates both the invalidate encoding and
    // correct XCC grouping in one shot. ----
    if (poll_stage(1, &hp[0], hl[0], 0u, e0, PROBE_CAP)) s_fail = 1;
    __syncthreads();

    // ---- unanimous vote through one packed agent counter ----
    if (tid == 0) {
        unsigned myok = s_fail ? 0u : 1u;
        __hip_atomic_fetch_add(&ctl[16 + xcd], 0x10000u | myok,
                               __ATOMIC_RELAXED, __HIP_MEMORY_SCOPE_AGENT);
        unsigned v = 0, done = 0;
        long long b0 = (long long)__builtin_amdgcn_s_memrealtime();
        for (;;) {
            v = __hip_atomic_load(&ctl[16 + xcd], __ATOMIC_RELAXED,
                                  __HIP_MEMORY_SCOPE_AGENT);
            if ((v >> 16) >= NROLES) { done = 1; break; }
            if ((long long)__builtin_amdgcn_s_memrealtime() - b0 > 4 * REG_TICKS) break;
        }
        s_go = done;
        s_mode = (done && (v & 0xFFFFu) == NROLES) ? 1u : 0u;
        s_fail = 0;
    }
    __syncthreads();
    if (!s_go) return;            // WG-uniform (essentially unreachable)
    const int fast = (int)s_mode;

    // Fallback housekeeping: agent groups on xcd>=2 bow out (avoid 8x MALL
    // contention); xcd 0 and 1 run redundantly. Fast groups all run.
    if (!fast && xcd >= 2) return;
    // Agent mode republishes init tags at the coherence point (fast-era init
    // stores are dirty-in-L2 only; same values, benign either way).
    if (!fast && tid < RPG)
        st_h(0, &hp[(size_t)role * RPG + tid], pack_hv(0.f, 0u));

    for (int t = 1; t <= T_STEPS; ++t) {
        float prev = 0.f;
        if (l < 4) prev = bf2f(pre[(size_t)(t - 1) * HID + rowbase + l]);

        const ull* src = &hp[((t - 1) & 1) * HID];
        float* dst = hl[(t - 1) & 1];
        if (poll_stage(fast, src, dst, (unsigned)(t - 1), e0, RUN_CAP)) s_abort = 1;
        __syncthreads();
        if (s_abort) break;       // WG-uniform (flag set before the barrier)

        float s0 = 0.f, s1 = 0.f, s2 = 0.f, s3 = 0.f;
#pragma unroll
        for (int j = 0; j < 4; ++j) {
            float4 hv = *(const float4*)&dst[4 * l + 256 * j];
            s0 = fmaf(wv[0][j].x, hv.x, s0); s0 = fmaf(wv[0][j].y, hv.y, s0);
            s0 = fmaf(wv[0][j].z, hv.z, s0); s0 = fmaf(wv[0][j].w, hv.w, s0);
            s1 = fmaf(wv[1][j].x, hv.x, s1); s1 = fmaf(wv[1][j].y, hv.y, s1);
            s1 = fmaf(wv[1][j].z, hv.z, s1); s1 = fmaf(wv[1][j].w, hv.w, s1);
            s2 = fmaf(wv[2][j].x, hv.x, s2); s2 = fmaf(wv[2][j].y, hv.y, s2);
            s2 = fmaf(wv[2][j].z, hv.z, s2); s2 = fmaf(wv[2][j].w, hv.w, s2);
            s3 = fmaf(wv[3][j].x, hv.x, s3); s3 = fmaf(wv[3][j].y, hv.y, s3);
            s3 = fmaf(wv[3][j].z, hv.z, s3); s3 = fmaf(wv[3][j].w, hv.w, s3);
        }
        s0 = wave_sum(s0); s1 = wave_sum(s1); s2 = wave_sum(s2); s3 = wave_sum(s3);

        if (l < 4) {
            float sv = (l == 0) ? s0 : (l == 1) ? s1 : (l == 2) ? s2 : s3;
            float h = tanhf(prev + sv);
            st_h(fast, &hp[((size_t)(t & 1)) * HID + rowbase + l],
                 pack_hv(h, (unsigned)t));
        }
        // two-deep parity buffer: no trailing barrier needed (poll success for
        // step t+1 implies all waves finished step t's LDS reads).
    }
    if (s_abort) return;          // aborted group never writes out

    // ---- final projection: out = h_T . W_h2o^T + b_h2o ----
    // Every complete group writes identical bytes; redundant race is benign.
    {
        const ull* src = &hp[(T_STEPS & 1) * HID];
        float* dst = hl[0];
        if (poll_stage(fast, src, dst, (unsigned)T_STEPS, e0, RUN_CAP)) s_abort = 1;
        __syncthreads();
        if (s_abort) return;

        float s0 = 0.f, s1 = 0.f, s2 = 0.f, s3 = 0.f;
#pragma unroll
        for (int j = 0; j < 4; ++j) {
            float4 hv = *(const float4*)&dst[4 * l + 256 * j];
            float4 w0 = *(const float4*)&Wo[(size_t)(rowbase + 0) * 1024 + 4 * l + 256 * j];
            float4 w1 = *(const float4*)&Wo[(size_t)(rowbase + 1) * 1024 + 4 * l + 256 * j];
            float4 w2 = *(const float4*)&Wo[(size_t)(rowbase + 2) * 1024 + 4 * l + 256 * j];
            float4 w3 = *(const float4*)&Wo[(size_t)(rowbase + 3) * 1024 + 4 * l + 256 * j];
            s0 = fmaf(w0.x, hv.x, s0); s0 = fmaf(w0.y, hv.y, s0);
            s0 = fmaf(w0.z, hv.z, s0); s0 = fmaf(w0.w, hv.w, s0);
            s1 = fmaf(w1.x, hv.x, s1); s1 = fmaf(w1.y, hv.y, s1);
            s1 = fmaf(w1.z, hv.z, s1); s1 = fmaf(w1.w, hv.w, s1);
            s2 = fmaf(w2.x, hv.x, s2); s2 = fmaf(w2.y, hv.y, s2);
            s2 = fmaf(w2.z, hv.z, s2); s2 = fmaf(w2.w, hv.w, s2);
            s3 = fmaf(w3.x, hv.x, s3); s3 = fmaf(w3.y, hv.y, s3);
            s3 = fmaf(w3.z, hv.z, s3); s3 = fmaf(w3.w, hv.w, s3);
        }
        s0 = wave_sum(s0); s1 = wave_sum(s1); s2 = wave_sum(s2); s3 = wave_sum(s3);
        if (l < 4) {
            float sv = (l == 0) ? s0 : (l == 1) ? s1 : (l == 2) ? s2 : s3;
            out[rowbase + l] = sv + bo[rowbase + l];
        }
    }
}

extern "C" void kernel_launch(void* const* d_in, const int* in_sizes, int n_in,
                              void* d_out, int out_size, void* d_ws, size_t ws_size,
                              hipStream_t stream) {
    const float* x     = (const float*)d_in[0];   // (1, 32768, 1024)
    const float* W_i2h = (const float*)d_in[1];   // (1024, 2048)
    const float* b_i2h = (const float*)d_in[2];   // (1024,)
    const float* W_h2o = (const float*)d_in[3];   // (1024, 1024)
    const float* b_h2o = (const float*)d_in[4];   // (1024,)
    float* out = (float*)d_out;

    unsigned short* pre = (unsigned short*)d_ws;                       // 64 MiB bf16
    ull* hp_all = (ull*)((char*)d_ws + (size_t)T_STEPS * HID * sizeof(unsigned short));
    unsigned* ctl = (unsigned*)((char*)hp_all + (size_t)NXCD * 2 * HID * sizeof(ull));

    pre_gemm<<<dim3(T_STEPS / BM, HID / BN), 256, 0, stream>>>(
        x, W_i2h, b_i2h, pre, hp_all, ctl);
    rnn_rec<<<NWG_LAUNCH, 256, 0, stream>>>(
        pre, W_i2h, W_h2o, b_h2o, out, hp_all, ctl);
}